// Round 11
// baseline (270.384 us; speedup 1.0000x reference)
//
#include <hip/hip_runtime.h>

// ---------------------------------------------------------------------------
// GCN + MHA + gated fuse + LayerNorm, MI355X (gfx950).
// R11: fused GEMM -> 8-phase 256x256 retry with the R7 spill fixed:
//      __launch_bounds__(512,1) (256-VGPR budget; R7's (512,2) capped at 128
//      -> 55MB scratch) + R10's verified conflict-free LDS quad swizzle
//      (pre-swizzled global source col, same XOR on read col).
//      Out-proj/gate GEMMs, attn, agg, LN unchanged from R10.
// ---------------------------------------------------------------------------

typedef __attribute__((ext_vector_type(8))) short b16x8;   // 8 bf16 = 4 VGPRs
typedef __attribute__((ext_vector_type(4))) float f32x4;

using gu32 = __attribute__((address_space(1))) const unsigned int;
using lu32 = __attribute__((address_space(3))) unsigned int;

constexpr int N  = 1024;
constexpr int B  = 8;
constexpr int D  = 768;
constexpr int H  = 8;
constexpr int DH = 96;
constexpr int E  = 16384;
constexpr int M  = N * B;          // 8192 rows, row r = n*B + b
constexpr float LN_EPS = 1e-5f;

#define DEV static __device__ __forceinline__
#define GLOAD(SRC, DST) __builtin_amdgcn_global_load_lds((gu32*)(SRC), (lu32*)(DST), 16, 0, 0)

DEV unsigned short f2b(float f) {           // f32 -> bf16 RNE
  unsigned u = __float_as_uint(f);
  u += 0x7fffu + ((u >> 16) & 1u);
  return (unsigned short)(u >> 16);
}
DEV float b2f(unsigned short h) { return __uint_as_float(((unsigned)h) << 16); }

// ---------------------------------------------------------------------------
// merged cast kernel: 5 f32->bf16 segments in one launch (float4 per thread)
// ---------------------------------------------------------------------------
constexpr int CS0 = 1572864;            // x:    M*768/4
constexpr int CS1 = CS0 + 147456;       // gcnW: 768*768/4
constexpr int CS2 = CS1 + 442368;       // ipw:  2304*768/4
constexpr int CS3 = CS2 + 147456;       // opw:  768*768/4
constexpr int CS4 = CS3 + 294912;       // gw:   768*1536/4
__global__ void cast_all_kernel(
    const float* __restrict__ x, const float* __restrict__ gcnW,
    const float* __restrict__ ipw, const float* __restrict__ opw,
    const float* __restrict__ gw,
    unsigned short* __restrict__ xb16, unsigned short* __restrict__ wcat,
    unsigned short* __restrict__ wout, unsigned short* __restrict__ wgate) {
  const int i = blockIdx.x * 256 + threadIdx.x;
  if (i >= CS4) return;
  const float* in; unsigned short* out; int off;
  if (i < CS0)      { in = x;    out = xb16;           off = i; }
  else if (i < CS1) { in = gcnW; out = wcat;           off = i - CS0; }
  else if (i < CS2) { in = ipw;  out = wcat + 589824;  off = i - CS1; }
  else if (i < CS3) { in = opw;  out = wout;           off = i - CS2; }
  else              { in = gw;   out = wgate;          off = i - CS3; }
  float4 v = ((const float4*)in)[off];
  ushort4 o;
  o.x = f2b(v.x); o.y = f2b(v.y); o.z = f2b(v.z); o.w = f2b(v.w);
  ((ushort4*)out)[off] = o;
}

__global__ void zero_i32_kernel(int* __restrict__ p, int n) {
  int i = blockIdx.x * 256 + threadIdx.x;
  if (i < n) p[i] = 0;
}

// count in-degree per (b, dst). edge_index layout [B,2,E].
__global__ void edge_count_kernel(const int* __restrict__ ei, int* __restrict__ cnt) {
  int i = blockIdx.x * 256 + threadIdx.x;      // B*E threads exactly
  int b = i >> 14, e = i & (E - 1);
  int dst = ei[(b << 15) + E + e];
  atomicAdd(&cnt[(b << 10) + dst], 1);
}

// per-batch exclusive scan of counts (1024 entries) + dinv = rsqrt(1+cnt)
__global__ __launch_bounds__(1024) void scan_offs_kernel(
    const int* __restrict__ cnt, int* __restrict__ offs,
    int* __restrict__ cursor, float* __restrict__ dinv) {
  __shared__ int buf[1024];
  const int b = blockIdx.x, i = threadIdx.x, g = (b << 10) + i;
  const int c = cnt[g];
  buf[i] = c;
  __syncthreads();
  for (int off = 1; off < 1024; off <<= 1) {
    int t = (i >= off) ? buf[i - off] : 0;
    __syncthreads();
    buf[i] += t;
    __syncthreads();
  }
  const int excl = buf[i] - c;
  offs[g] = excl;
  cursor[g] = excl;
  dinv[g] = rsqrtf((float)(c + 1));           // self-loop included
}

// stores SRC (not edge id) -> agg loop has one fewer dependent load
__global__ void edge_fill_kernel(const int* __restrict__ ei,
                                 int* __restrict__ cursor, int* __restrict__ elist) {
  int i = blockIdx.x * 256 + threadIdx.x;
  int b = i >> 14, e = i & (E - 1);
  int src = ei[(b << 15) + e];
  int dst = ei[(b << 15) + E + e];
  int slot = atomicAdd(&cursor[(b << 10) + dst], 1);
  elist[(b << 14) + slot] = src;
}

// ---------------------------------------------------------------------------
// FUSED 256x256 GEMM, 8 waves, 4 phases/K-tile (K-tile=64 as 2x 32-planes):
//   phase: {ds_read subtile(swz) ; stage half of t+1 ; [vmcnt(4) @ph1,3] ;
//           barrier ; lgkmcnt(0) ; setprio(1) ; 16 MFMA ; setprio(0) ; barrier}
// vmcnt(4) counted FIFO: ph1 waits ks1(t), ph3 waits ks0(t+1); never 0 mid-loop.
// LDS quad swizzle (R10-verified conflict-free): slot(row,quad) holds global
// quad^((row>>1)&3); linear LDS dest, pre-swizzled global source.
// __launch_bounds__(512,1): 256-VGPR budget (acc=128 + frags fits, no spill).
// ---------------------------------------------------------------------------
__global__ __launch_bounds__(512, 1) void gemm_fused256(
    const unsigned short* __restrict__ A, const unsigned short* __restrict__ W,
    const float* __restrict__ bias,
    void* __restrict__ p0, void* __restrict__ p1, void* __restrict__ p2,
    void* __restrict__ p3) {
  constexpr int K = 768;
  __shared__ __align__(16) unsigned short sA[2][2][256][32];  // [buf][ks][row][col]
  __shared__ __align__(16) unsigned short sB[2][2][256][32];
  const int tid = threadIdx.x;
  const int lane = tid & 63, wid = tid >> 6;        // 8 waves
  const int wm = wid >> 2, wn = wid & 3;            // 2 x 4
  const int m0 = blockIdx.y * 256, n0 = blockIdx.x * 256;
  const int l15 = lane & 15, lhi = lane >> 4;
  const int rcol = (lhi ^ ((l15 >> 1) & 3)) * 8;          // read-side swizzle
  const int scol = (((tid & 3) ^ ((tid >> 3) & 3))) * 8;  // source pre-swizzle

  f32x4 acc[8][4] = {};

  // staging source bases (per-lane): row = tid>>2 (0..127), quad pre-swizzled
  const unsigned short* pa = A + ((size_t)(m0 + (tid >> 2))) * K + scol;
  const unsigned short* pb = W + ((size_t)(n0 + (tid >> 2))) * K + scol;
  constexpr size_t RS = (size_t)128 * K;            // +128 rows

  // prologue: stage tile 0, order B-ks0, A-ks0, B-ks1, A-ks1 (8 loads)
  GLOAD(pb,           &sB[0][0][wid * 16][0]);
  GLOAD(pb + RS,      &sB[0][0][128 + wid * 16][0]);
  GLOAD(pa,           &sA[0][0][wid * 16][0]);
  GLOAD(pa + RS,      &sA[0][0][128 + wid * 16][0]);
  GLOAD(pb + 32,      &sB[0][1][wid * 16][0]);
  GLOAD(pb + 32 + RS, &sB[0][1][128 + wid * 16][0]);
  GLOAD(pa + 32,      &sA[0][1][wid * 16][0]);
  GLOAD(pa + 32 + RS, &sA[0][1][128 + wid * 16][0]);
  asm volatile("s_waitcnt vmcnt(4)" ::: "memory");  // ks0 planes landed
  __builtin_amdgcn_s_barrier();

  for (int t = 0; t < 12; ++t) {
    const int p = t & 1;
    const bool stg = (t < 11);
    const int kn = (t + 1) * 64;          // next-tile k offset (elements)
    b16x8 af[4], bf[4];

    // ============ phase 0: wave-rows 0-63, ks=0 ============
#pragma unroll
    for (int cf = 0; cf < 4; ++cf)
      bf[cf] = *(const b16x8*)&sB[p][0][wn * 64 + cf * 16 + l15][rcol];
#pragma unroll
    for (int rf = 0; rf < 4; ++rf)
      af[rf] = *(const b16x8*)&sA[p][0][wm * 128 + rf * 16 + l15][rcol];
    if (stg) {                            // stage B-ks0(t+1)
      GLOAD(pb + kn,      &sB[p ^ 1][0][wid * 16][0]);
      GLOAD(pb + kn + RS, &sB[p ^ 1][0][128 + wid * 16][0]);
    }
    __builtin_amdgcn_sched_barrier(0);
    __builtin_amdgcn_s_barrier();
    asm volatile("s_waitcnt lgkmcnt(0)" ::: "memory");
    __builtin_amdgcn_sched_barrier(0);
    __builtin_amdgcn_s_setprio(1);
#pragma unroll
    for (int rf = 0; rf < 4; ++rf)
#pragma unroll
      for (int cf = 0; cf < 4; ++cf)
        acc[rf][cf] = __builtin_amdgcn_mfma_f32_16x16x32_bf16(af[rf], bf[cf], acc[rf][cf], 0, 0, 0);
    __builtin_amdgcn_s_setprio(0);
    __builtin_amdgcn_sched_barrier(0);
    __builtin_amdgcn_s_barrier();

    // ============ phase 1: wave-rows 64-127, ks=0 ============
#pragma unroll
    for (int rf = 0; rf < 4; ++rf)
      af[rf] = *(const b16x8*)&sA[p][0][wm * 128 + 64 + rf * 16 + l15][rcol];
    if (stg) {                            // stage A-ks0(t+1)
      GLOAD(pa + kn,      &sA[p ^ 1][0][wid * 16][0]);
      GLOAD(pa + kn + RS, &sA[p ^ 1][0][128 + wid * 16][0]);
    }
    __builtin_amdgcn_sched_barrier(0);
    if (stg) asm volatile("s_waitcnt vmcnt(4)" ::: "memory");   // ks1(t) ready
    else     asm volatile("s_waitcnt vmcnt(0)" ::: "memory");
    __builtin_amdgcn_s_barrier();
    asm volatile("s_waitcnt lgkmcnt(0)" ::: "memory");
    __builtin_amdgcn_sched_barrier(0);
    __builtin_amdgcn_s_setprio(1);
#pragma unroll
    for (int rf = 0; rf < 4; ++rf)
#pragma unroll
      for (int cf = 0; cf < 4; ++cf)
        acc[4 + rf][cf] = __builtin_amdgcn_mfma_f32_16x16x32_bf16(af[rf], bf[cf], acc[4 + rf][cf], 0, 0, 0);
    __builtin_amdgcn_s_setprio(0);
    __builtin_amdgcn_sched_barrier(0);
    __builtin_amdgcn_s_barrier();

    // ============ phase 2: wave-rows 0-63, ks=1 ============
#pragma unroll
    for (int cf = 0; cf < 4; ++cf)
      bf[cf] = *(const b16x8*)&sB[p][1][wn * 64 + cf * 16 + l15][rcol];
#pragma unroll
    for (int rf = 0; rf < 4; ++rf)
      af[rf] = *(const b16x8*)&sA[p][1][wm * 128 + rf * 16 + l15][rcol];
    if (stg) {                            // stage B-ks1(t+1)
      GLOAD(pb + kn + 32,      &sB[p ^ 1][1][wid * 16][0]);
      GLOAD(pb + kn + 32 + RS, &sB[p ^ 1][1][128 + wid * 16][0]);
    }
    __builtin_amdgcn_sched_barrier(0);
    __builtin_amdgcn_s_barrier();
    asm volatile("s_waitcnt lgkmcnt(0)" ::: "memory");
    __builtin_amdgcn_sched_barrier(0);
    __builtin_amdgcn_s_setprio(1);
#pragma unroll
    for (int rf = 0; rf < 4; ++rf)
#pragma unroll
      for (int cf = 0; cf < 4; ++cf)
        acc[rf][cf] = __builtin_amdgcn_mfma_f32_16x16x32_bf16(af[rf], bf[cf], acc[rf][cf], 0, 0, 0);
    __builtin_amdgcn_s_setprio(0);
    __builtin_amdgcn_sched_barrier(0);
    __builtin_amdgcn_s_barrier();

    // ============ phase 3: wave-rows 64-127, ks=1 ============
#pragma unroll
    for (int rf = 0; rf < 4; ++rf)
      af[rf] = *(const b16x8*)&sA[p][1][wm * 128 + 64 + rf * 16 + l15][rcol];
    if (stg) {                            // stage A-ks1(t+1)
      GLOAD(pa + kn + 32,      &sA[p ^ 1][1][wid * 16][0]);
      GLOAD(pa + kn + 32 + RS, &sA[p ^ 1][1][128 + wid * 16][0]);
    }
    __builtin_amdgcn_sched_barrier(0);
    if (stg) asm volatile("s_waitcnt vmcnt(4)" ::: "memory");   // ks0(t+1) ready
    __builtin_amdgcn_s_barrier();
    asm volatile("s_waitcnt lgkmcnt(0)" ::: "memory");
    __builtin_amdgcn_sched_barrier(0);
    __builtin_amdgcn_s_setprio(1);
#pragma unroll
    for (int rf = 0; rf < 4; ++rf)
#pragma unroll
      for (int cf = 0; cf < 4; ++cf)
        acc[4 + rf][cf] = __builtin_amdgcn_mfma_f32_16x16x32_bf16(af[rf], bf[cf], acc[4 + rf][cf], 0, 0, 0);
    __builtin_amdgcn_s_setprio(0);
    __builtin_amdgcn_sched_barrier(0);
    __builtin_amdgcn_s_barrier();
  }

  // epilogue: C/D layout col = lane&15, row = (lane>>4)*4 + reg  [HW-verified]
#pragma unroll
  for (int rg = 0; rg < 8; ++rg) {
#pragma unroll
    for (int cf = 0; cf < 4; ++cf) {
      const int c = n0 + wn * 64 + cf * 16 + l15;
      const float bv = (c < 768) ? 0.0f : bias[c - 768];
#pragma unroll
      for (int g = 0; g < 4; ++g) {
        const int r = m0 + wm * 128 + rg * 16 + lhi * 4 + g;
        float v = acc[rg][cf][g] + bv;
        const int n = r >> 3, b = r & 7;
        if (c < 768) {
          ((unsigned short*)p0)[((size_t)((b << 10) + n)) * 768 + c] = f2b(v);
        } else {
          const int cc2 = c - 768;
          const int sec = cc2 / 768, cc = cc2 - sec * 768;
          const int hd = cc / 96, dh = cc - hd * 96;
          unsigned short* dst =
              (sec == 0) ? (unsigned short*)p1
                         : (sec == 1 ? (unsigned short*)p2 : (unsigned short*)p3);
          size_t idx;
          if (sec < 2) idx = ((size_t)((b * 8 + hd) * 1024 + n)) * 96 + dh;  // [B,H,N,DH]
          else         idx = ((size_t)((b * 8 + hd) * 96 + dh)) * 1024 + n;  // V^T
          dst[idx] = f2b(v);
        }
      }
    }
  }
}

// ---------------------------------------------------------------------------
// 128-tile GEMM (R10: counted-vmcnt 2-phase, conflict-free swizzled LDS)
// for out-proj and gate.
// ---------------------------------------------------------------------------
constexpr int EPI_ATTN  = 1;  // -> cat bf16 [r, 768+c]
constexpr int EPI_GATE  = 2;  // -> sigmoid -> gate bf16 [r,c]

template <int EPI, int BN, int K, int GX, int GY>
__global__ __launch_bounds__(256) void gemm_bt(
    const unsigned short* __restrict__ A, const unsigned short* __restrict__ W,
    const float* __restrict__ bias, void* __restrict__ p0) {
  constexpr int NW = BN / 32;          // n-fragments per wave
  constexpr int NT = K / 32;           // K-steps
  __shared__ __align__(16) unsigned short sA[2][128][32];
  __shared__ __align__(16) unsigned short sB[2][BN][32];
  const int tid = threadIdx.x;
  const int lane = tid & 63, wid = tid >> 6;
  const int wm = wid >> 1, wn = wid & 1;
  const int bid = blockIdx.x;
  const int xcd = bid & 7, slot = bid >> 3;
  const int by = xcd * (GY / 8) + slot / GX;
  const int bx = slot % GX;
  const int m0 = by * 128, n0 = bx * BN;
  const int l15 = lane & 15, lhi = lane >> 4;
  const int srow = lane >> 2;
  const int scol = (((lane & 3) ^ ((lane >> 3) & 3))) * 8;
  const int rcol = ((lhi ^ ((l15 >> 1) & 3))) * 8;

  f32x4 acc[4][NW] = {};

  const unsigned short* pa = A + ((size_t)(m0 + wid * 32 + srow)) * K + scol;
  const unsigned short* pb = W + ((size_t)(n0 + wid * (BN / 4) + srow)) * K + scol;

  auto stage = [&](int buf) {
    GLOAD(pa,          &sA[buf][wid * 32][0]);
    GLOAD(pa + 16 * K, &sA[buf][wid * 32 + 16][0]);
    GLOAD(pb,          &sB[buf][wid * (BN / 4)][0]);
    if constexpr (BN == 128) GLOAD(pb + 16 * K, &sB[buf][wid * 32 + 16][0]);
    pa += 32; pb += 32;
  };

  stage(0);
  int cur = 0;
  for (int kt = 0; kt < NT; ++kt) {
    if (kt + 1 < NT) {
      stage(cur ^ 1);
      if constexpr (BN == 128) asm volatile("s_waitcnt vmcnt(4)" ::: "memory");
      else                     asm volatile("s_waitcnt vmcnt(3)" ::: "memory");
    } else {
      asm volatile("s_waitcnt vmcnt(0)" ::: "memory");
    }
    __builtin_amdgcn_s_barrier();
    __builtin_amdgcn_sched_barrier(0);

    b16x8 af[4], bfr[NW];
#pragma unroll
    for (int i = 0; i < 4; ++i)
      af[i] = *(const b16x8*)&sA[cur][wm * 64 + i * 16 + l15][rcol];
#pragma unroll
    for (int j = 0; j < NW; ++j)
      bfr[j] = *(const b16x8*)&sB[cur][wn * (BN / 2) + j * 16 + l15][rcol];
#pragma unroll
    for (int i = 0; i < 4; ++i)
#pragma unroll
      for (int j = 0; j < NW; ++j)
        acc[i][j] = __builtin_amdgcn_mfma_f32_16x16x32_bf16(af[i], bfr[j], acc[i][j], 0, 0, 0);

    __builtin_amdgcn_sched_barrier(0);
    __builtin_amdgcn_s_barrier();
    cur ^= 1;
  }

#pragma unroll
  for (int i = 0; i < 4; ++i) {
#pragma unroll
    for (int j = 0; j < NW; ++j) {
      const int c = n0 + wn * (BN / 2) + j * 16 + l15;
      const float bv = bias[c];
#pragma unroll
      for (int g = 0; g < 4; ++g) {
        const int r = m0 + wm * 64 + i * 16 + lhi * 4 + g;
        float v = acc[i][j][g] + bv;
        if constexpr (EPI == EPI_ATTN) {
          ((unsigned short*)p0)[(size_t)r * 1536 + 768 + c] = f2b(v);
        } else {  // EPI_GATE -> bf16 gate
          ((unsigned short*)p0)[(size_t)r * 768 + c] =
              f2b(1.0f / (1.0f + __expf(-v)));
        }
      }
    }
  }
}

// ---------------------------------------------------------------------------
// flash-style attention, no-max softmax; prefetch in NAMED registers.
// 4 waves x 16 q-rows; XCD-grouped 1D grid (K/V L2-resident per XCD).
// ---------------------------------------------------------------------------
__global__ __launch_bounds__(256) void attn_kernel(
    const unsigned short* __restrict__ qb, const unsigned short* __restrict__ kb,
    const unsigned short* __restrict__ vb, unsigned short* __restrict__ ctx) {
  __shared__ __align__(16) unsigned short sK[64][104];  // [key][dh], pad 96->104
  __shared__ __align__(16) unsigned short sV[96][72];   // [dh][key], pad 64->72
  __shared__ __align__(16) unsigned short sP[4][16][72];
  const int tid = threadIdx.x, lane = tid & 63, wid = tid >> 6;
  const int l15 = lane & 15, lhi = lane >> 4;
  const int bid = blockIdx.x;
  const int xcd = bid & 7, slot = bid >> 3;
  const int bh = xcd * 8 + (slot >> 4);
  const int q0 = (slot & 15) * 64;
  const float SCL = 0.14724445f;  // (1/sqrt(96)) * log2(e)

  b16x8 qf[3];
  const size_t qbase = ((size_t)bh * 1024 + q0 + wid * 16 + l15) * 96 + lhi * 8;
#pragma unroll
  for (int ks = 0; ks < 3; ++ks) qf[ks] = *(const b16x8*)(qb + qbase + ks * 32);

  const int c0 = tid, c1 = 256 + tid, c2 = 512 + tid;
  const unsigned short* kp0 = kb + ((size_t)bh * 1024 + c0 / 12) * 96 + (c0 % 12) * 8;
  const unsigned short* kp1 = kb + ((size_t)bh * 1024 + c1 / 12) * 96 + (c1 % 12) * 8;
  const unsigned short* kp2 = kb + ((size_t)bh * 1024 + c2 / 12) * 96 + (c2 % 12) * 8;
  const unsigned short* vp0 = vb + ((size_t)bh * 96 + (c0 >> 3)) * 1024 + (c0 & 7) * 8;
  const unsigned short* vp1 = vb + ((size_t)bh * 96 + (c1 >> 3)) * 1024 + (c1 & 7) * 8;
  const unsigned short* vp2 = vb + ((size_t)bh * 96 + (c2 >> 3)) * 1024 + (c2 & 7) * 8;
  unsigned short* sk0 = &sK[c0 / 12][(c0 % 12) * 8];
  unsigned short* sk1 = &sK[c1 / 12][(c1 % 12) * 8];
  unsigned short* sk2 = &sK[c2 / 12][(c2 % 12) * 8];
  unsigned short* sv0 = &sV[c0 >> 3][(c0 & 7) * 8];
  unsigned short* sv1 = &sV[c1 >> 3][(c1 & 7) * 8];
  unsigned short* sv2 = &sV[c2 >> 3][(c2 & 7) * 8];

  uint4 k0 = *(const uint4*)kp0, k1 = *(const uint4*)kp1, k2 = *(const uint4*)kp2;
  uint4 v0 = *(const uint4*)vp0, v1 = *(const uint4*)vp1, v2 = *(const uint4*)vp2;

  f32x4 accO[6] = {};
  float ssum[4] = {0.f, 0.f, 0.f, 0.f};

  for (int kt = 0; kt < 16; ++kt) {
    __syncthreads();
    *(uint4*)sk0 = k0; *(uint4*)sk1 = k1; *(uint4*)sk2 = k2;
    *(uint4*)sv0 = v0; *(uint4*)sv1 = v1; *(uint4*)sv2 = v2;
    __syncthreads();
    if (kt < 15) {
      kp0 += 64 * 96; kp1 += 64 * 96; kp2 += 64 * 96;
      vp0 += 64;      vp1 += 64;      vp2 += 64;
      k0 = *(const uint4*)kp0; k1 = *(const uint4*)kp1; k2 = *(const uint4*)kp2;
      v0 = *(const uint4*)vp0; v1 = *(const uint4*)vp1; v2 = *(const uint4*)vp2;
    }

    f32x4 sf[4] = {};
#pragma unroll
    for (int f = 0; f < 4; ++f) {
#pragma unroll
      for (int ks = 0; ks < 3; ++ks) {
        b16x8 kf = *(const b16x8*)&sK[f * 16 + l15][ks * 32 + lhi * 8];
        sf[f] = __builtin_amdgcn_mfma_f32_16x16x32_bf16(qf[ks], kf, sf[f], 0, 0, 0);
      }
    }

#pragma unroll
    for (int g = 0; g < 4; ++g) {
#pragma unroll
      for (int f = 0; f < 4; ++f) {
        const float pv = exp2f(sf[f][g] * SCL);
        sP[wid][lhi * 4 + g][f * 16 + l15] = f2b(pv);
        ssum[g] += pv;
      }
    }

#pragma unroll
    for (int ks = 0; ks < 2; ++ks) {
      b16x8 pa = *(const b16x8*)&sP[wid][l15][ks * 32 + lhi * 8];
#pragma unroll
      for (int o = 0; o < 6; ++o) {
        b16x8 vf = *(const b16x8*)&sV[o * 16 + l15][ks * 32 + lhi * 8];
        accO[o] = __builtin_amdgcn_mfma_f32_16x16x32_bf16(pa, vf, accO[o], 0, 0, 0);
      }
    }
  }

#pragma unroll
  for (int g = 0; g < 4; ++g) {
#pragma unroll
    for (int msk = 1; msk < 16; msk <<= 1) ssum[g] += __shfl_xor(ssum[g], msk);
  }

  const int b = bh >> 3, hd = bh & 7;
  float rinv[4];
#pragma unroll
  for (int g = 0; g < 4; ++g) rinv[g] = 1.0f / ssum[g];
#pragma unroll
  for (int o = 0; o < 6; ++o)
#pragma unroll
    for (int g = 0; g < 4; ++g) {
      const int qrow = q0 + wid * 16 + lhi * 4 + g;
      ctx[((size_t)qrow * 8 + b) * 768 + hd * 96 + o * 16 + l15] =
          f2b(accO[o][g] * rinv[g]);
    }
}

// ---------------------------------------------------------------------------
// GCN aggregation: block (192 thr) per (b,n); 2 independent gathers per iter;
// writes bf16 into cat16 only (LN reads gcn from cat16).
// ---------------------------------------------------------------------------
__global__ __launch_bounds__(192) void gcn_agg_kernel(
    const unsigned short* __restrict__ h16,
    const int* __restrict__ cnt, const int* __restrict__ offs,
    const int* __restrict__ elist, const float* __restrict__ dinv,
    const float* __restrict__ gcn_b, unsigned short* __restrict__ cat16) {
  const int bn = blockIdx.x;  // b*1024 + n
  const int b = bn >> 10, n = bn & 1023;
  const int d = threadIdx.x * 4;
  const float dn = dinv[bn];
  const size_t hrow = (size_t)bn * 768;
  ushort4 hv = *(const ushort4*)(h16 + hrow + d);
  float a0 = dn * dn * b2f(hv.x), a1 = dn * dn * b2f(hv.y);
  float a2 = dn * dn * b2f(hv.z), a3 = dn * dn * b2f(hv.w);
  const int st = offs[bn], cv = cnt[bn];
  const int* ep = elist + (b << 14) + st;
  int i = 0;
  for (; i + 2 <= cv; i += 2) {           // two independent gathers in flight
    const int s0 = ep[i], s1 = ep[i + 1];
    const float nv0 = dinv[(b << 10) + s0] * dn;
    const float nv1 = dinv[(b << 10) + s1] * dn;
    const ushort4 r0 = *(const ushort4*)(h16 + ((size_t)((b << 10) + s0)) * 768 + d);
    const ushort4 r1 = *(const ushort4*)(h16 + ((size_t)((b << 10) + s1)) * 768 + d);
    a0 += nv0 * b2f(r0.x) + nv1 * b2f(r1.x);
    a1 += nv0 * b2f(r0.y) + nv1 * b2f(r1.y);
    a2 += nv0 * b2f(r0.z) + nv1 * b2f(r1.z);
    a3 += nv0 * b2f(r0.w) + nv1 * b2f(r1.w);
  }
  if (i < cv) {
    const int s0 = ep[i];
    const float nv0 = dinv[(b << 10) + s0] * dn;
    const ushort4 r0 = *(const ushort4*)(h16 + ((size_t)((b << 10) + s0)) * 768 + d);
    a0 += nv0 * b2f(r0.x); a1 += nv0 * b2f(r0.y);
    a2 += nv0 * b2f(r0.z); a3 += nv0 * b2f(r0.w);
  }
  const float4 bb = *(const float4*)(gcn_b + d);
  a0 += bb.x; a1 += bb.y; a2 += bb.z; a3 += bb.w;
  const size_t crow = ((size_t)n * 8 + b) * 1536;
  ushort4 co; co.x = f2b(a0); co.y = f2b(a1); co.z = f2b(a2); co.w = f2b(a3);
  *(ushort4*)(cat16 + crow + d) = co;
}

// ---------------------------------------------------------------------------
// gate-blend + residual + LayerNorm. block (192 thr) per row.
// gate/gcn/attn read as bf16 (gate16, cat16); x residual f32.
// ---------------------------------------------------------------------------
__global__ __launch_bounds__(192) void ln_fuse_kernel(
    const unsigned short* __restrict__ gate16,
    const unsigned short* __restrict__ cat16,
    const float* __restrict__ x,
    const float* __restrict__ lng, const float* __restrict__ lnb,
    float* __restrict__ out) {
  const int r = blockIdx.x;
  const int t = threadIdx.x, lane = t & 63, wid = t >> 6;   // 3 waves
  const int d = t * 4;
  const size_t xrow = (size_t)r * 768;
  const size_t crow = (size_t)r * 1536;
  const ushort4 gv = *(const ushort4*)(gate16 + xrow + d);
  const ushort4 cv = *(const ushort4*)(cat16 + crow + d);        // gcn
  const ushort4 av = *(const ushort4*)(cat16 + crow + 768 + d);  // attn
  const float4 xv = *(const float4*)(x + xrow + d);
  const float g0 = b2f(gv.x), g1 = b2f(gv.y), g2 = b2f(gv.z), g3 = b2f(gv.w);
  float f0 = g0 * b2f(cv.x) + (1.f - g0) * b2f(av.x) + xv.x;
  float f1 = g1 * b2f(cv.y) + (1.f - g1) * b2f(av.y) + xv.y;
  float f2 = g2 * b2f(cv.z) + (1.f - g2) * b2f(av.z) + xv.z;
  float f3 = g3 * b2f(cv.w) + (1.f - g3) * b2f(av.w) + xv.w;
  float s1 = f0 + f1 + f2 + f3;
  float s2 = f0 * f0 + f1 * f1 + f2 * f2 + f3 * f3;
#pragma unroll
  for (int msk = 1; msk < 64; msk <<= 1) {
    s1 += __shfl_xor(s1, msk);
    s2 += __shfl_xor(s2, msk);
  }
  __shared__ float p1[3], p2[3];
  if (lane == 0) { p1[wid] = s1; p2[wid] = s2; }
  __syncthreads();
  s1 = p1[0] + p1[1] + p1[2];
  s2 = p2[0] + p2[1] + p2[2];
  const float mu = s1 * (1.f / 768.f);
  float var = s2 * (1.f / 768.f) - mu * mu;
  var = fmaxf(var, 0.f);
  const float rstd = rsqrtf(var + LN_EPS);
  const float4 lg = *(const float4*)(lng + d);
  const float4 lb = *(const float4*)(lnb + d);
  float4 o;
  o.x = (f0 - mu) * rstd * lg.x + lb.x;
  o.y = (f1 - mu) * rstd * lg.y + lb.y;
  o.z = (f2 - mu) * rstd * lg.z + lb.z;
  o.w = (f3 - mu) * rstd * lg.w + lb.w;
  *(float4*)(out + xrow + d) = o;
}

// ---------------------------------------------------------------------------
extern "C" void kernel_launch(void* const* d_in, const int* in_sizes, int n_in,
                              void* d_out, int out_size, void* d_ws, size_t ws_size,
                              hipStream_t stream) {
  const float* x     = (const float*)d_in[0];
  const int*   ei    = (const int*)d_in[1];
  const float* gcnW  = (const float*)d_in[2];
  const float* gcnb  = (const float*)d_in[3];
  const float* ipw   = (const float*)d_in[4];
  const float* ipb   = (const float*)d_in[5];
  const float* opw   = (const float*)d_in[6];
  const float* opb   = (const float*)d_in[7];
  const float* gw    = (const float*)d_in[8];
  const float* gb    = (const float*)d_in[9];
  const float* lng   = (const float*)d_in[10];
  const float* lnb   = (const float*)d_in[11];
  float* out = (float*)d_out;

  char* p = (char*)d_ws;
  auto alloc = [&](size_t bytes) { void* q = p; p += (bytes + 255) & ~(size_t)255; return q; };

  unsigned short* xb16  = (unsigned short*)alloc((size_t)M * 768 * 2);   // also ctx16
  unsigned short* wcat  = (unsigned short*)alloc((size_t)3072 * 768 * 2); // [wgcn;wqkv]
  unsigned short* wout  = (unsigned short*)alloc((size_t)768 * 768 * 2);
  unsigned short* wgate = (unsigned short*)alloc((size_t)768 * 1536 * 2);
  unsigned short* qb    = (unsigned short*)alloc((size_t)B * H * N * DH * 2); // also gate16
  unsigned short* kb    = (unsigned short*)alloc((size_t)B * H * N * DH * 2);
  unsigned short* vb    = (unsigned short*)alloc((size_t)B * H * DH * N * 2);
  unsigned short* h16   = (unsigned short*)alloc((size_t)M * 768 * 2);
  unsigned short* cat16 = (unsigned short*)alloc((size_t)M * 1536 * 2);
  int* cnt    = (int*)alloc(8192 * 4);
  int* offs   = (int*)alloc(8192 * 4);
  int* cursor = (int*)alloc(8192 * 4);
  float* dinv = (float*)alloc(8192 * 4);
  int* elist  = (int*)alloc((size_t)B * E * 4);

  // safe aliases (serial-stream ordering makes these race-free):
  unsigned short* ctx16  = xb16;  // written by attn AFTER last read of xb16 (fused gemm)
  unsigned short* gate16 = qb;    // written by gate gemm AFTER attn reads qb

  // 1) all casts in one launch
  cast_all_kernel<<<(CS4 + 255) / 256, 256, 0, stream>>>(
      x, gcnW, ipw, opw, gw, xb16, wcat, wout, wgate);

  // 2) CSR build for GCN aggregation
  zero_i32_kernel<<<32, 256, 0, stream>>>(cnt, 8192);
  edge_count_kernel<<<(B * E) / 256, 256, 0, stream>>>(ei, cnt);
  scan_offs_kernel<<<8, 1024, 0, stream>>>(cnt, offs, cursor, dinv);
  edge_fill_kernel<<<(B * E) / 256, 256, 0, stream>>>(ei, cursor, elist);

  // 3) fused GCN-linear + QKV GEMM (256-tile 8-wave); attn; agg; out-proj; gate
  gemm_fused256<<<dim3(12, 32), 512, 0, stream>>>(
      xb16, wcat, ipb, (void*)h16, (void*)qb, (void*)kb, (void*)vb);
  attn_kernel<<<1024, 256, 0, stream>>>(qb, kb, vb, ctx16);
  gcn_agg_kernel<<<8192, 192, 0, stream>>>(h16, cnt, offs, elist, dinv, gcnb, cat16);
  gemm_bt<EPI_ATTN, 64, 768, 12, 64><<<768, 256, 0, stream>>>(
      ctx16, wout, opb, (void*)cat16);
  gemm_bt<EPI_GATE, 64, 1536, 12, 64><<<768, 256, 0, stream>>>(
      cat16, wgate, gb, (void*)gate16);

  // 4) gate blend + residual + LayerNorm
  ln_fuse_kernel<<<8192, 192, 0, stream>>>(gate16, cat16, x, lng, lnb, out);
}

// Round 12
// 257.530 us; speedup vs baseline: 1.0499x; 1.0499x over previous
//
#include <hip/hip_runtime.h>

// ---------------------------------------------------------------------------
// GCN + MHA + gated fuse + LayerNorm, MI355X (gfx950).
// R12: revert to R10 (best known: 2-phase 128x128 counted-vmcnt GEMMs with
//      conflict-free swizzled LDS + XCD-contiguous grid). 8-phase 256x256
//      falsified twice at this shape (compiler spills acc despite bounds;
//      grid tail + 12 K-tiles + 1 blk/CU break its design point).
//      New: T5 s_setprio around attn MFMA clusters (m191-proven regime:
//      independent blocks, multiple blocks/CU -> +4-7% on attn).
// ---------------------------------------------------------------------------

typedef __attribute__((ext_vector_type(8))) short b16x8;   // 8 bf16 = 4 VGPRs
typedef __attribute__((ext_vector_type(4))) float f32x4;

using gu32 = __attribute__((address_space(1))) const unsigned int;
using lu32 = __attribute__((address_space(3))) unsigned int;

constexpr int N  = 1024;
constexpr int B  = 8;
constexpr int D  = 768;
constexpr int H  = 8;
constexpr int DH = 96;
constexpr int E  = 16384;
constexpr int M  = N * B;          // 8192 rows, row r = n*B + b
constexpr float LN_EPS = 1e-5f;

#define DEV static __device__ __forceinline__
#define GLOAD(SRC, DST) __builtin_amdgcn_global_load_lds((gu32*)(SRC), (lu32*)(DST), 16, 0, 0)

DEV unsigned short f2b(float f) {           // f32 -> bf16 RNE
  unsigned u = __float_as_uint(f);
  u += 0x7fffu + ((u >> 16) & 1u);
  return (unsigned short)(u >> 16);
}
DEV float b2f(unsigned short h) { return __uint_as_float(((unsigned)h) << 16); }

// ---------------------------------------------------------------------------
// merged cast kernel: 5 f32->bf16 segments in one launch (float4 per thread)
// ---------------------------------------------------------------------------
constexpr int CS0 = 1572864;            // x:    M*768/4
constexpr int CS1 = CS0 + 147456;       // gcnW: 768*768/4
constexpr int CS2 = CS1 + 442368;       // ipw:  2304*768/4
constexpr int CS3 = CS2 + 147456;       // opw:  768*768/4
constexpr int CS4 = CS3 + 294912;       // gw:   768*1536/4
__global__ void cast_all_kernel(
    const float* __restrict__ x, const float* __restrict__ gcnW,
    const float* __restrict__ ipw, const float* __restrict__ opw,
    const float* __restrict__ gw,
    unsigned short* __restrict__ xb16, unsigned short* __restrict__ wcat,
    unsigned short* __restrict__ wout, unsigned short* __restrict__ wgate) {
  const int i = blockIdx.x * 256 + threadIdx.x;
  if (i >= CS4) return;
  const float* in; unsigned short* out; int off;
  if (i < CS0)      { in = x;    out = xb16;           off = i; }
  else if (i < CS1) { in = gcnW; out = wcat;           off = i - CS0; }
  else if (i < CS2) { in = ipw;  out = wcat + 589824;  off = i - CS1; }
  else if (i < CS3) { in = opw;  out = wout;           off = i - CS2; }
  else              { in = gw;   out = wgate;          off = i - CS3; }
  float4 v = ((const float4*)in)[off];
  ushort4 o;
  o.x = f2b(v.x); o.y = f2b(v.y); o.z = f2b(v.z); o.w = f2b(v.w);
  ((ushort4*)out)[off] = o;
}

__global__ void zero_i32_kernel(int* __restrict__ p, int n) {
  int i = blockIdx.x * 256 + threadIdx.x;
  if (i < n) p[i] = 0;
}

// count in-degree per (b, dst). edge_index layout [B,2,E].
__global__ void edge_count_kernel(const int* __restrict__ ei, int* __restrict__ cnt) {
  int i = blockIdx.x * 256 + threadIdx.x;      // B*E threads exactly
  int b = i >> 14, e = i & (E - 1);
  int dst = ei[(b << 15) + E + e];
  atomicAdd(&cnt[(b << 10) + dst], 1);
}

// per-batch exclusive scan of counts (1024 entries) + dinv = rsqrt(1+cnt)
__global__ __launch_bounds__(1024) void scan_offs_kernel(
    const int* __restrict__ cnt, int* __restrict__ offs,
    int* __restrict__ cursor, float* __restrict__ dinv) {
  __shared__ int buf[1024];
  const int b = blockIdx.x, i = threadIdx.x, g = (b << 10) + i;
  const int c = cnt[g];
  buf[i] = c;
  __syncthreads();
  for (int off = 1; off < 1024; off <<= 1) {
    int t = (i >= off) ? buf[i - off] : 0;
    __syncthreads();
    buf[i] += t;
    __syncthreads();
  }
  const int excl = buf[i] - c;
  offs[g] = excl;
  cursor[g] = excl;
  dinv[g] = rsqrtf((float)(c + 1));           // self-loop included
}

// stores SRC (not edge id) -> agg loop has one fewer dependent load
__global__ void edge_fill_kernel(const int* __restrict__ ei,
                                 int* __restrict__ cursor, int* __restrict__ elist) {
  int i = blockIdx.x * 256 + threadIdx.x;
  int b = i >> 14, e = i & (E - 1);
  int src = ei[(b << 15) + e];
  int dst = ei[(b << 15) + E + e];
  int slot = atomicAdd(&cursor[(b << 10) + dst], 1);
  elist[(b << 14) + slot] = src;
}

// ---------------------------------------------------------------------------
// bf16 MFMA GEMM:  C[M x Ncol] = A[M x K] @ W[Ncol x K]^T (+ bias)
// BM=128, BN in {64,128}, BK=32, 256 threads (4 waves, 2x2).
// Double-buffered, counted vmcnt. LDS 16B-quad XOR swizzle by (row>>1)&3
// (conflict-free, R10-verified: SQ_LDS_BANK_CONFLICT 4.7M -> 0):
//   write side: linear LDS dest, global source col pre-swizzled;
//   read side:  col quad = lhi ^ ((l15>>1)&3).
// XCD-contiguous swizzle: 1D grid, y = xcd*(GY/8)+slot/GX, x = slot%GX.
// ---------------------------------------------------------------------------
constexpr int EPI_FUSED = 0;  // c<768 -> h bf16 [B,N,D]; else qkv split
constexpr int EPI_ATTN  = 1;  // -> cat bf16 [r, 768+c]
constexpr int EPI_GATE  = 2;  // -> sigmoid -> gate bf16 [r,c]

template <int EPI, int BN, int K, int GX, int GY>
__global__ __launch_bounds__(256) void gemm_bt(
    const unsigned short* __restrict__ A, const unsigned short* __restrict__ W,
    const float* __restrict__ bias,
    void* __restrict__ p0, void* __restrict__ p1, void* __restrict__ p2,
    void* __restrict__ p3) {
  constexpr int NW = BN / 32;          // n-fragments per wave
  constexpr int NT = K / 32;           // K-steps
  __shared__ __align__(16) unsigned short sA[2][128][32];
  __shared__ __align__(16) unsigned short sB[2][BN][32];
  const int tid = threadIdx.x;
  const int lane = tid & 63, wid = tid >> 6;
  const int wm = wid >> 1, wn = wid & 1;
  // XCD-contiguous mapping: each XCD owns GY/8 consecutive row-panels
  const int bid = blockIdx.x;
  const int xcd = bid & 7, slot = bid >> 3;
  const int by = xcd * (GY / 8) + slot / GX;
  const int bx = slot % GX;
  const int m0 = by * 128, n0 = bx * BN;
  const int l15 = lane & 15, lhi = lane >> 4;
  const int srow = lane >> 2;
  // pre-swizzled source column: LDS slot (row=lane>>2, quad=lane&3) must hold
  // global quad (lane&3) ^ s(row), s(row) = (row>>1)&3 = (lane>>3)&3
  const int scol = (((lane & 3) ^ ((lane >> 3) & 3))) * 8;
  // read-side swizzle for fragment loads (row = base16 + l15)
  const int rcol = ((lhi ^ ((l15 >> 1) & 3))) * 8;

  f32x4 acc[4][NW] = {};

  const unsigned short* pa = A + ((size_t)(m0 + wid * 32 + srow)) * K + scol;
  const unsigned short* pb = W + ((size_t)(n0 + wid * (BN / 4) + srow)) * K + scol;

  auto stage = [&](int buf) {
    GLOAD(pa,          &sA[buf][wid * 32][0]);
    GLOAD(pa + 16 * K, &sA[buf][wid * 32 + 16][0]);
    GLOAD(pb,          &sB[buf][wid * (BN / 4)][0]);
    if constexpr (BN == 128) GLOAD(pb + 16 * K, &sB[buf][wid * 32 + 16][0]);
    pa += 32; pb += 32;
  };

  stage(0);
  int cur = 0;
  for (int kt = 0; kt < NT; ++kt) {
    if (kt + 1 < NT) {
      stage(cur ^ 1);
      if constexpr (BN == 128) asm volatile("s_waitcnt vmcnt(4)" ::: "memory");
      else                     asm volatile("s_waitcnt vmcnt(3)" ::: "memory");
    } else {
      asm volatile("s_waitcnt vmcnt(0)" ::: "memory");
    }
    __builtin_amdgcn_s_barrier();          // all waves' tile-kt loads landed
    __builtin_amdgcn_sched_barrier(0);

    b16x8 af[4], bfr[NW];
#pragma unroll
    for (int i = 0; i < 4; ++i)
      af[i] = *(const b16x8*)&sA[cur][wm * 64 + i * 16 + l15][rcol];
#pragma unroll
    for (int j = 0; j < NW; ++j)
      bfr[j] = *(const b16x8*)&sB[cur][wn * (BN / 2) + j * 16 + l15][rcol];
#pragma unroll
    for (int i = 0; i < 4; ++i)
#pragma unroll
      for (int j = 0; j < NW; ++j)
        acc[i][j] = __builtin_amdgcn_mfma_f32_16x16x32_bf16(af[i], bfr[j], acc[i][j], 0, 0, 0);

    __builtin_amdgcn_sched_barrier(0);     // reads stay above this barrier
    __builtin_amdgcn_s_barrier();          // readers done before buf reuse
    cur ^= 1;
  }

  // epilogue: C/D layout col = lane&15, row = (lane>>4)*4 + reg  [HW-verified]
#pragma unroll
  for (int i = 0; i < 4; ++i) {
#pragma unroll
    for (int j = 0; j < NW; ++j) {
      const int c = n0 + wn * (BN / 2) + j * 16 + l15;
      float bv;
      if constexpr (EPI == EPI_FUSED) bv = (c < 768) ? 0.0f : bias[c - 768];
      else bv = bias[c];
#pragma unroll
      for (int g = 0; g < 4; ++g) {
        const int r = m0 + wm * 64 + i * 16 + lhi * 4 + g;
        float v = acc[i][j][g] + bv;
        if constexpr (EPI == EPI_FUSED) {
          const int n = r >> 3, b = r & 7;
          if (c < 768) {
            ((unsigned short*)p0)[((size_t)((b << 10) + n)) * 768 + c] = f2b(v);
          } else {
            const int cc2 = c - 768;
            const int sec = cc2 / 768, cc = cc2 - sec * 768;
            const int hd = cc / 96, dh = cc - hd * 96;
            unsigned short* dst =
                (sec == 0) ? (unsigned short*)p1
                           : (sec == 1 ? (unsigned short*)p2 : (unsigned short*)p3);
            size_t idx;
            if (sec < 2) idx = ((size_t)((b * 8 + hd) * 1024 + n)) * 96 + dh;  // [B,H,N,DH]
            else         idx = ((size_t)((b * 8 + hd) * 96 + dh)) * 1024 + n;  // V^T
            dst[idx] = f2b(v);
          }
        } else if constexpr (EPI == EPI_ATTN) {
          ((unsigned short*)p0)[(size_t)r * 1536 + 768 + c] = f2b(v);
        } else {  // EPI_GATE -> bf16 gate
          ((unsigned short*)p0)[(size_t)r * 768 + c] =
              f2b(1.0f / (1.0f + __expf(-v)));
        }
      }
    }
  }
}

// ---------------------------------------------------------------------------
// flash-style attention, no-max softmax; prefetch in NAMED registers
// (arrays/lambda spill to scratch: R3 measured 404 MB/dispatch writes).
// 4 waves x 16 q-rows; XCD-grouped 1D grid (K/V L2-resident per XCD).
// T5: setprio(1) around MFMA clusters (independent blocks at different
// phases on each CU -> scheduler arbitration pays; m191 regime).
// ---------------------------------------------------------------------------
__global__ __launch_bounds__(256) void attn_kernel(
    const unsigned short* __restrict__ qb, const unsigned short* __restrict__ kb,
    const unsigned short* __restrict__ vb, unsigned short* __restrict__ ctx) {
  __shared__ __align__(16) unsigned short sK[64][104];  // [key][dh], pad 96->104
  __shared__ __align__(16) unsigned short sV[96][72];   // [dh][key], pad 64->72
  __shared__ __align__(16) unsigned short sP[4][16][72];
  const int tid = threadIdx.x, lane = tid & 63, wid = tid >> 6;
  const int l15 = lane & 15, lhi = lane >> 4;
  const int bid = blockIdx.x;
  const int xcd = bid & 7, slot = bid >> 3;
  const int bh = xcd * 8 + (slot >> 4);
  const int q0 = (slot & 15) * 64;
  const float SCL = 0.14724445f;  // (1/sqrt(96)) * log2(e)

  b16x8 qf[3];
  const size_t qbase = ((size_t)bh * 1024 + q0 + wid * 16 + l15) * 96 + lhi * 8;
#pragma unroll
  for (int ks = 0; ks < 3; ++ks) qf[ks] = *(const b16x8*)(qb + qbase + ks * 32);

  const int c0 = tid, c1 = 256 + tid, c2 = 512 + tid;
  const unsigned short* kp0 = kb + ((size_t)bh * 1024 + c0 / 12) * 96 + (c0 % 12) * 8;
  const unsigned short* kp1 = kb + ((size_t)bh * 1024 + c1 / 12) * 96 + (c1 % 12) * 8;
  const unsigned short* kp2 = kb + ((size_t)bh * 1024 + c2 / 12) * 96 + (c2 % 12) * 8;
  const unsigned short* vp0 = vb + ((size_t)bh * 96 + (c0 >> 3)) * 1024 + (c0 & 7) * 8;
  const unsigned short* vp1 = vb + ((size_t)bh * 96 + (c1 >> 3)) * 1024 + (c1 & 7) * 8;
  const unsigned short* vp2 = vb + ((size_t)bh * 96 + (c2 >> 3)) * 1024 + (c2 & 7) * 8;
  unsigned short* sk0 = &sK[c0 / 12][(c0 % 12) * 8];
  unsigned short* sk1 = &sK[c1 / 12][(c1 % 12) * 8];
  unsigned short* sk2 = &sK[c2 / 12][(c2 % 12) * 8];
  unsigned short* sv0 = &sV[c0 >> 3][(c0 & 7) * 8];
  unsigned short* sv1 = &sV[c1 >> 3][(c1 & 7) * 8];
  unsigned short* sv2 = &sV[c2 >> 3][(c2 & 7) * 8];

  uint4 k0 = *(const uint4*)kp0, k1 = *(const uint4*)kp1, k2 = *(const uint4*)kp2;
  uint4 v0 = *(const uint4*)vp0, v1 = *(const uint4*)vp1, v2 = *(const uint4*)vp2;

  f32x4 accO[6] = {};
  float ssum[4] = {0.f, 0.f, 0.f, 0.f};

  for (int kt = 0; kt < 16; ++kt) {
    __syncthreads();
    *(uint4*)sk0 = k0; *(uint4*)sk1 = k1; *(uint4*)sk2 = k2;
    *(uint4*)sv0 = v0; *(uint4*)sv1 = v1; *(uint4*)sv2 = v2;
    __syncthreads();
    if (kt < 15) {
      kp0 += 64 * 96; kp1 += 64 * 96; kp2 += 64 * 96;
      vp0 += 64;      vp1 += 64;      vp2 += 64;
      k0 = *(const uint4*)kp0; k1 = *(const uint4*)kp1; k2 = *(const uint4*)kp2;
      v0 = *(const uint4*)vp0; v1 = *(const uint4*)vp1; v2 = *(const uint4*)vp2;
    }

    // S = Q K^T  (wave: 16 q-rows x 64 keys)
    f32x4 sf[4] = {};
    __builtin_amdgcn_s_setprio(1);
#pragma unroll
    for (int f = 0; f < 4; ++f) {
#pragma unroll
      for (int ks = 0; ks < 3; ++ks) {
        b16x8 kf = *(const b16x8*)&sK[f * 16 + l15][ks * 32 + lhi * 8];
        sf[f] = __builtin_amdgcn_mfma_f32_16x16x32_bf16(qf[ks], kf, sf[f], 0, 0, 0);
      }
    }
    __builtin_amdgcn_s_setprio(0);

#pragma unroll
    for (int g = 0; g < 4; ++g) {
#pragma unroll
      for (int f = 0; f < 4; ++f) {
        const float pv = exp2f(sf[f][g] * SCL);
        sP[wid][lhi * 4 + g][f * 16 + l15] = f2b(pv);
        ssum[g] += pv;
      }
    }

    // O += P V   (per-wave sP; in-wave lgkmcnt ordering suffices)
    __builtin_amdgcn_s_setprio(1);
#pragma unroll
    for (int ks = 0; ks < 2; ++ks) {
      b16x8 pa = *(const b16x8*)&sP[wid][l15][ks * 32 + lhi * 8];
#pragma unroll
      for (int o = 0; o < 6; ++o) {
        b16x8 vf = *(const b16x8*)&sV[o * 16 + l15][ks * 32 + lhi * 8];
        accO[o] = __builtin_amdgcn_mfma_f32_16x16x32_bf16(pa, vf, accO[o], 0, 0, 0);
      }
    }
    __builtin_amdgcn_s_setprio(0);
  }

#pragma unroll
  for (int g = 0; g < 4; ++g) {
#pragma unroll
    for (int msk = 1; msk < 16; msk <<= 1) ssum[g] += __shfl_xor(ssum[g], msk);
  }

  const int b = bh >> 3, hd = bh & 7;
  float rinv[4];
#pragma unroll
  for (int g = 0; g < 4; ++g) rinv[g] = 1.0f / ssum[g];
#pragma unroll
  for (int o = 0; o < 6; ++o)
#pragma unroll
    for (int g = 0; g < 4; ++g) {
      const int qrow = q0 + wid * 16 + lhi * 4 + g;
      ctx[((size_t)qrow * 8 + b) * 768 + hd * 96 + o * 16 + l15] =
          f2b(accO[o][g] * rinv[g]);
    }
}

// ---------------------------------------------------------------------------
// GCN aggregation: block (192 thr) per (b,n); 2 independent gathers per iter;
// writes bf16 into cat16 only (LN reads gcn from cat16).
// ---------------------------------------------------------------------------
__global__ __launch_bounds__(192) void gcn_agg_kernel(
    const unsigned short* __restrict__ h16,
    const int* __restrict__ cnt, const int* __restrict__ offs,
    const int* __restrict__ elist, const float* __restrict__ dinv,
    const float* __restrict__ gcn_b, unsigned short* __restrict__ cat16) {
  const int bn = blockIdx.x;  // b*1024 + n
  const int b = bn >> 10, n = bn & 1023;
  const int d = threadIdx.x * 4;
  const float dn = dinv[bn];
  const size_t hrow = (size_t)bn * 768;
  ushort4 hv = *(const ushort4*)(h16 + hrow + d);
  float a0 = dn * dn * b2f(hv.x), a1 = dn * dn * b2f(hv.y);
  float a2 = dn * dn * b2f(hv.z), a3 = dn * dn * b2f(hv.w);
  const int st = offs[bn], cv = cnt[bn];
  const int* ep = elist + (b << 14) + st;
  int i = 0;
  for (; i + 2 <= cv; i += 2) {           // two independent gathers in flight
    const int s0 = ep[i], s1 = ep[i + 1];
    const float nv0 = dinv[(b << 10) + s0] * dn;
    const float nv1 = dinv[(b << 10) + s1] * dn;
    const ushort4 r0 = *(const ushort4*)(h16 + ((size_t)((b << 10) + s0)) * 768 + d);
    const ushort4 r1 = *(const ushort4*)(h16 + ((size_t)((b << 10) + s1)) * 768 + d);
    a0 += nv0 * b2f(r0.x) + nv1 * b2f(r1.x);
    a1 += nv0 * b2f(r0.y) + nv1 * b2f(r1.y);
    a2 += nv0 * b2f(r0.z) + nv1 * b2f(r1.z);
    a3 += nv0 * b2f(r0.w) + nv1 * b2f(r1.w);
  }
  if (i < cv) {
    const int s0 = ep[i];
    const float nv0 = dinv[(b << 10) + s0] * dn;
    const ushort4 r0 = *(const ushort4*)(h16 + ((size_t)((b << 10) + s0)) * 768 + d);
    a0 += nv0 * b2f(r0.x); a1 += nv0 * b2f(r0.y);
    a2 += nv0 * b2f(r0.z); a3 += nv0 * b2f(r0.w);
  }
  const float4 bb = *(const float4*)(gcn_b + d);
  a0 += bb.x; a1 += bb.y; a2 += bb.z; a3 += bb.w;
  const size_t crow = ((size_t)n * 8 + b) * 1536;
  ushort4 co; co.x = f2b(a0); co.y = f2b(a1); co.z = f2b(a2); co.w = f2b(a3);
  *(ushort4*)(cat16 + crow + d) = co;
}

// ---------------------------------------------------------------------------
// gate-blend + residual + LayerNorm. block (192 thr) per row.
// gate/gcn/attn read as bf16 (gate16, cat16); x residual f32.
// ---------------------------------------------------------------------------
__global__ __launch_bounds__(192) void ln_fuse_kernel(
    const unsigned short* __restrict__ gate16,
    const unsigned short* __restrict__ cat16,
    const float* __restrict__ x,
    const float* __restrict__ lng, const float* __restrict__ lnb,
    float* __restrict__ out) {
  const int r = blockIdx.x;
  const int t = threadIdx.x, lane = t & 63, wid = t >> 6;   // 3 waves
  const int d = t * 4;
  const size_t xrow = (size_t)r * 768;
  const size_t crow = (size_t)r * 1536;
  const ushort4 gv = *(const ushort4*)(gate16 + xrow + d);
  const ushort4 cv = *(const ushort4*)(cat16 + crow + d);        // gcn
  const ushort4 av = *(const ushort4*)(cat16 + crow + 768 + d);  // attn
  const float4 xv = *(const float4*)(x + xrow + d);
  const float g0 = b2f(gv.x), g1 = b2f(gv.y), g2 = b2f(gv.z), g3 = b2f(gv.w);
  float f0 = g0 * b2f(cv.x) + (1.f - g0) * b2f(av.x) + xv.x;
  float f1 = g1 * b2f(cv.y) + (1.f - g1) * b2f(av.y) + xv.y;
  float f2 = g2 * b2f(cv.z) + (1.f - g2) * b2f(av.z) + xv.z;
  float f3 = g3 * b2f(cv.w) + (1.f - g3) * b2f(av.w) + xv.w;
  float s1 = f0 + f1 + f2 + f3;
  float s2 = f0 * f0 + f1 * f1 + f2 * f2 + f3 * f3;
#pragma unroll
  for (int msk = 1; msk < 64; msk <<= 1) {
    s1 += __shfl_xor(s1, msk);
    s2 += __shfl_xor(s2, msk);
  }
  __shared__ float p1[3], p2[3];
  if (lane == 0) { p1[wid] = s1; p2[wid] = s2; }
  __syncthreads();
  s1 = p1[0] + p1[1] + p1[2];
  s2 = p2[0] + p2[1] + p2[2];
  const float mu = s1 * (1.f / 768.f);
  float var = s2 * (1.f / 768.f) - mu * mu;
  var = fmaxf(var, 0.f);
  const float rstd = rsqrtf(var + LN_EPS);
  const float4 lg = *(const float4*)(lng + d);
  const float4 lb = *(const float4*)(lnb + d);
  float4 o;
  o.x = (f0 - mu) * rstd * lg.x + lb.x;
  o.y = (f1 - mu) * rstd * lg.y + lb.y;
  o.z = (f2 - mu) * rstd * lg.z + lb.z;
  o.w = (f3 - mu) * rstd * lg.w + lb.w;
  *(float4*)(out + xrow + d) = o;
}

// ---------------------------------------------------------------------------
extern "C" void kernel_launch(void* const* d_in, const int* in_sizes, int n_in,
                              void* d_out, int out_size, void* d_ws, size_t ws_size,
                              hipStream_t stream) {
  const float* x     = (const float*)d_in[0];
  const int*   ei    = (const int*)d_in[1];
  const float* gcnW  = (const float*)d_in[2];
  const float* gcnb  = (const float*)d_in[3];
  const float* ipw   = (const float*)d_in[4];
  const float* ipb   = (const float*)d_in[5];
  const float* opw   = (const float*)d_in[6];
  const float* opb   = (const float*)d_in[7];
  const float* gw    = (const float*)d_in[8];
  const float* gb    = (const float*)d_in[9];
  const float* lng   = (const float*)d_in[10];
  const float* lnb   = (const float*)d_in[11];
  float* out = (float*)d_out;

  char* p = (char*)d_ws;
  auto alloc = [&](size_t bytes) { void* q = p; p += (bytes + 255) & ~(size_t)255; return q; };

  unsigned short* xb16  = (unsigned short*)alloc((size_t)M * 768 * 2);   // also ctx16
  unsigned short* wcat  = (unsigned short*)alloc((size_t)3072 * 768 * 2); // [wgcn;wqkv]
  unsigned short* wout  = (unsigned short*)alloc((size_t)768 * 768 * 2);
  unsigned short* wgate = (unsigned short*)alloc((size_t)768 * 1536 * 2);
  unsigned short* qb    = (unsigned short*)alloc((size_t)B * H * N * DH * 2); // also gate16
  unsigned short* kb    = (unsigned short*)alloc((size_t)B * H * N * DH * 2);
  unsigned short* vb    = (unsigned short*)alloc((size_t)B * H * DH * N * 2);
  unsigned short* h16   = (unsigned short*)alloc((size_t)M * 768 * 2);
  unsigned short* cat16 = (unsigned short*)alloc((size_t)M * 1536 * 2);
  int* cnt    = (int*)alloc(8192 * 4);
  int* offs   = (int*)alloc(8192 * 4);
  int* cursor = (int*)alloc(8192 * 4);
  float* dinv = (float*)alloc(8192 * 4);
  int* elist  = (int*)alloc((size_t)B * E * 4);

  // safe aliases (serial-stream ordering makes these race-free):
  unsigned short* ctx16  = xb16;  // written by attn AFTER last read of xb16 (fused gemm)
  unsigned short* gate16 = qb;    // written by gate gemm AFTER attn reads qb

  // 1) all casts in one launch
  cast_all_kernel<<<(CS4 + 255) / 256, 256, 0, stream>>>(
      x, gcnW, ipw, opw, gw, xb16, wcat, wout, wgate);

  // 2) CSR build for GCN aggregation
  zero_i32_kernel<<<32, 256, 0, stream>>>(cnt, 8192);
  edge_count_kernel<<<(B * E) / 256, 256, 0, stream>>>(ei, cnt);
  scan_offs_kernel<<<8, 1024, 0, stream>>>(cnt, offs, cursor, dinv);
  edge_fill_kernel<<<(B * E) / 256, 256, 0, stream>>>(ei, cursor, elist);

  // 3) fused GCN-linear + QKV GEMM; attention; aggregation; out-proj; gate
  gemm_bt<EPI_FUSED, 128, 768, 24, 64><<<1536, 256, 0, stream>>>(
      xb16, wcat, ipb, (void*)h16, (void*)qb, (void*)kb, (void*)vb);
  attn_kernel<<<1024, 256, 0, stream>>>(qb, kb, vb, ctx16);
  gcn_agg_kernel<<<8192, 192, 0, stream>>>(h16, cnt, offs, elist, dinv, gcnb, cat16);
  gemm_bt<EPI_ATTN, 64, 768, 12, 64><<<768, 256, 0, stream>>>(
      ctx16, wout, opb, (void*)cat16, nullptr, nullptr, nullptr);
  gemm_bt<EPI_GATE, 64, 1536, 12, 64><<<768, 256, 0, stream>>>(
      cat16, wgate, gb, (void*)gate16, nullptr, nullptr, nullptr);

  // 4) gate blend + residual + LayerNorm
  ln_fuse_kernel<<<8192, 192, 0, stream>>>(gate16, cat16, x, lng, lnb, out);
}

// Round 13
// 256.409 us; speedup vs baseline: 1.0545x; 1.0044x over previous
//
#include <hip/hip_runtime.h>

// ---------------------------------------------------------------------------
// GCN + MHA + gated fuse + LayerNorm, MI355X (gfx950).
// R13: inter-kernel overlap — attn and gcn_agg are data-independent with
//      complementary pipes (MFMA+VALU vs gather-latency); merged into ONE
//      dispatch (m114: co-scheduled waves ~ max, not sum). agg gets
//      batch->XCD mapping (1.5MB/batch slice fits 4MB XCD L2). zero_i32 ->
//      hipMemsetAsync; edge_count folded into cast kernel (11 -> 9 launches).
//      GEMMs stay at R12 (proven structure ceiling ~87us for K=768).
// ---------------------------------------------------------------------------

typedef __attribute__((ext_vector_type(8))) short b16x8;   // 8 bf16 = 4 VGPRs
typedef __attribute__((ext_vector_type(4))) float f32x4;

using gu32 = __attribute__((address_space(1))) const unsigned int;
using lu32 = __attribute__((address_space(3))) unsigned int;

constexpr int N  = 1024;
constexpr int B  = 8;
constexpr int D  = 768;
constexpr int H  = 8;
constexpr int DH = 96;
constexpr int E  = 16384;
constexpr int M  = N * B;          // 8192 rows, row r = n*B + b
constexpr float LN_EPS = 1e-5f;

#define DEV static __device__ __forceinline__
#define GLOAD(SRC, DST) __builtin_amdgcn_global_load_lds((gu32*)(SRC), (lu32*)(DST), 16, 0, 0)

DEV unsigned short f2b(float f) {           // f32 -> bf16 RNE
  unsigned u = __float_as_uint(f);
  u += 0x7fffu + ((u >> 16) & 1u);
  return (unsigned short)(u >> 16);
}
DEV float b2f(unsigned short h) { return __uint_as_float(((unsigned)h) << 16); }

// ---------------------------------------------------------------------------
// merged cast (5 f32->bf16 segments) + edge_count kernel.
// blocks [0,10176): cast float4/thread; blocks [10176,10688): in-degree count.
// cnt must be zeroed beforehand (hipMemsetAsync, stream-ordered).
// ---------------------------------------------------------------------------
constexpr int CS0 = 1572864;            // x:    M*768/4
constexpr int CS1 = CS0 + 147456;       // gcnW: 768*768/4
constexpr int CS2 = CS1 + 442368;       // ipw:  2304*768/4
constexpr int CS3 = CS2 + 147456;       // opw:  768*768/4
constexpr int CS4 = CS3 + 294912;       // gw:   768*1536/4  (= 2605056 = 10176*256)
constexpr int CAST_BLOCKS = CS4 / 256;          // 10176
constexpr int CNT_BLOCKS  = (B * E) / 256;      // 512
__global__ void cast_count_kernel(
    const float* __restrict__ x, const float* __restrict__ gcnW,
    const float* __restrict__ ipw, const float* __restrict__ opw,
    const float* __restrict__ gw,
    unsigned short* __restrict__ xb16, unsigned short* __restrict__ wcat,
    unsigned short* __restrict__ wout, unsigned short* __restrict__ wgate,
    const int* __restrict__ ei, int* __restrict__ cnt) {
  const int blk = blockIdx.x;
  if (blk < CAST_BLOCKS) {
    const int i = blk * 256 + threadIdx.x;
    const float* in; unsigned short* out; int off;
    if (i < CS0)      { in = x;    out = xb16;           off = i; }
    else if (i < CS1) { in = gcnW; out = wcat;           off = i - CS0; }
    else if (i < CS2) { in = ipw;  out = wcat + 589824;  off = i - CS1; }
    else if (i < CS3) { in = opw;  out = wout;           off = i - CS2; }
    else              { in = gw;   out = wgate;          off = i - CS3; }
    float4 v = ((const float4*)in)[off];
    ushort4 o;
    o.x = f2b(v.x); o.y = f2b(v.y); o.z = f2b(v.z); o.w = f2b(v.w);
    ((ushort4*)out)[off] = o;
  } else {
    const int j = (blk - CAST_BLOCKS) * 256 + threadIdx.x;   // < B*E
    const int b = j >> 14, e = j & (E - 1);
    const int dst = ei[(b << 15) + E + e];
    atomicAdd(&cnt[(b << 10) + dst], 1);
  }
}

// per-batch exclusive scan of counts (1024 entries) + dinv = rsqrt(1+cnt)
__global__ __launch_bounds__(1024) void scan_offs_kernel(
    const int* __restrict__ cnt, int* __restrict__ offs,
    int* __restrict__ cursor, float* __restrict__ dinv) {
  __shared__ int buf[1024];
  const int b = blockIdx.x, i = threadIdx.x, g = (b << 10) + i;
  const int c = cnt[g];
  buf[i] = c;
  __syncthreads();
  for (int off = 1; off < 1024; off <<= 1) {
    int t = (i >= off) ? buf[i - off] : 0;
    __syncthreads();
    buf[i] += t;
    __syncthreads();
  }
  const int excl = buf[i] - c;
  offs[g] = excl;
  cursor[g] = excl;
  dinv[g] = rsqrtf((float)(c + 1));           // self-loop included
}

// stores SRC (not edge id) -> agg loop has one fewer dependent load
__global__ void edge_fill_kernel(const int* __restrict__ ei,
                                 int* __restrict__ cursor, int* __restrict__ elist) {
  int i = blockIdx.x * 256 + threadIdx.x;
  int b = i >> 14, e = i & (E - 1);
  int src = ei[(b << 15) + e];
  int dst = ei[(b << 15) + E + e];
  int slot = atomicAdd(&cursor[(b << 10) + dst], 1);
  elist[(b << 14) + slot] = src;
}

// ---------------------------------------------------------------------------
// bf16 MFMA GEMM (R12/R10 structure — proven ceiling for this shape):
// BM=128, BN in {64,128}, BK=32, double-buffered, counted vmcnt,
// conflict-free LDS quad swizzle, XCD-contiguous grid.
// ---------------------------------------------------------------------------
constexpr int EPI_FUSED = 0;  // c<768 -> h bf16 [B,N,D]; else qkv split
constexpr int EPI_ATTN  = 1;  // -> cat bf16 [r, 768+c]
constexpr int EPI_GATE  = 2;  // -> sigmoid -> gate bf16 [r,c]

template <int EPI, int BN, int K, int GX, int GY>
__global__ __launch_bounds__(256) void gemm_bt(
    const unsigned short* __restrict__ A, const unsigned short* __restrict__ W,
    const float* __restrict__ bias,
    void* __restrict__ p0, void* __restrict__ p1, void* __restrict__ p2,
    void* __restrict__ p3) {
  constexpr int NW = BN / 32;          // n-fragments per wave
  constexpr int NT = K / 32;           // K-steps
  __shared__ __align__(16) unsigned short sA[2][128][32];
  __shared__ __align__(16) unsigned short sB[2][BN][32];
  const int tid = threadIdx.x;
  const int lane = tid & 63, wid = tid >> 6;
  const int wm = wid >> 1, wn = wid & 1;
  const int bid = blockIdx.x;
  const int xcd = bid & 7, slot = bid >> 3;
  const int by = xcd * (GY / 8) + slot / GX;
  const int bx = slot % GX;
  const int m0 = by * 128, n0 = bx * BN;
  const int l15 = lane & 15, lhi = lane >> 4;
  const int srow = lane >> 2;
  const int scol = (((lane & 3) ^ ((lane >> 3) & 3))) * 8;  // pre-swizzled src
  const int rcol = ((lhi ^ ((l15 >> 1) & 3))) * 8;          // read-side swizzle

  f32x4 acc[4][NW] = {};

  const unsigned short* pa = A + ((size_t)(m0 + wid * 32 + srow)) * K + scol;
  const unsigned short* pb = W + ((size_t)(n0 + wid * (BN / 4) + srow)) * K + scol;

  auto stage = [&](int buf) {
    GLOAD(pa,          &sA[buf][wid * 32][0]);
    GLOAD(pa + 16 * K, &sA[buf][wid * 32 + 16][0]);
    GLOAD(pb,          &sB[buf][wid * (BN / 4)][0]);
    if constexpr (BN == 128) GLOAD(pb + 16 * K, &sB[buf][wid * 32 + 16][0]);
    pa += 32; pb += 32;
  };

  stage(0);
  int cur = 0;
  for (int kt = 0; kt < NT; ++kt) {
    if (kt + 1 < NT) {
      stage(cur ^ 1);
      if constexpr (BN == 128) asm volatile("s_waitcnt vmcnt(4)" ::: "memory");
      else                     asm volatile("s_waitcnt vmcnt(3)" ::: "memory");
    } else {
      asm volatile("s_waitcnt vmcnt(0)" ::: "memory");
    }
    __builtin_amdgcn_s_barrier();
    __builtin_amdgcn_sched_barrier(0);

    b16x8 af[4], bfr[NW];
#pragma unroll
    for (int i = 0; i < 4; ++i)
      af[i] = *(const b16x8*)&sA[cur][wm * 64 + i * 16 + l15][rcol];
#pragma unroll
    for (int j = 0; j < NW; ++j)
      bfr[j] = *(const b16x8*)&sB[cur][wn * (BN / 2) + j * 16 + l15][rcol];
#pragma unroll
    for (int i = 0; i < 4; ++i)
#pragma unroll
      for (int j = 0; j < NW; ++j)
        acc[i][j] = __builtin_amdgcn_mfma_f32_16x16x32_bf16(af[i], bfr[j], acc[i][j], 0, 0, 0);

    __builtin_amdgcn_sched_barrier(0);
    __builtin_amdgcn_s_barrier();
    cur ^= 1;
  }

  // epilogue: C/D layout col = lane&15, row = (lane>>4)*4 + reg  [HW-verified]
#pragma unroll
  for (int i = 0; i < 4; ++i) {
#pragma unroll
    for (int j = 0; j < NW; ++j) {
      const int c = n0 + wn * (BN / 2) + j * 16 + l15;
      float bv;
      if constexpr (EPI == EPI_FUSED) bv = (c < 768) ? 0.0f : bias[c - 768];
      else bv = bias[c];
#pragma unroll
      for (int g = 0; g < 4; ++g) {
        const int r = m0 + wm * 64 + i * 16 + lhi * 4 + g;
        float v = acc[i][j][g] + bv;
        if constexpr (EPI == EPI_FUSED) {
          const int n = r >> 3, b = r & 7;
          if (c < 768) {
            ((unsigned short*)p0)[((size_t)((b << 10) + n)) * 768 + c] = f2b(v);
          } else {
            const int cc2 = c - 768;
            const int sec = cc2 / 768, cc = cc2 - sec * 768;
            const int hd = cc / 96, dh = cc - hd * 96;
            unsigned short* dst =
                (sec == 0) ? (unsigned short*)p1
                           : (sec == 1 ? (unsigned short*)p2 : (unsigned short*)p3);
            size_t idx;
            if (sec < 2) idx = ((size_t)((b * 8 + hd) * 1024 + n)) * 96 + dh;  // [B,H,N,DH]
            else         idx = ((size_t)((b * 8 + hd) * 96 + dh)) * 1024 + n;  // V^T
            dst[idx] = f2b(v);
          }
        } else if constexpr (EPI == EPI_ATTN) {
          ((unsigned short*)p0)[(size_t)r * 1536 + 768 + c] = f2b(v);
        } else {  // EPI_GATE -> bf16 gate
          ((unsigned short*)p0)[(size_t)r * 768 + c] =
              f2b(1.0f / (1.0f + __expf(-v)));
        }
      }
    }
  }
}

// ---------------------------------------------------------------------------
// MERGED attention + GCN aggregation (data-independent, complementary pipes;
// m114: MFMA-waves and gather-waves co-schedule ~ max not sum).
// blocks [0,1024): flash attention (XCD-grouped by bid&7, as before).
// blocks [1024,9216): aggregation, batch->XCD mapping b = abid&7 so each
//   batch's 1.5MB h16 slice is resident in ONE XCD's 4MB L2.
// ---------------------------------------------------------------------------
__global__ __launch_bounds__(256) void attn_agg_kernel(
    const unsigned short* __restrict__ qb, const unsigned short* __restrict__ kb,
    const unsigned short* __restrict__ vb, unsigned short* __restrict__ ctx,
    const unsigned short* __restrict__ h16,
    const int* __restrict__ cnt, const int* __restrict__ offs,
    const int* __restrict__ elist, const float* __restrict__ dinv,
    const float* __restrict__ gcn_b, unsigned short* __restrict__ cat16) {
  __shared__ __align__(16) unsigned short sK[64][104];  // [key][dh], pad 96->104
  __shared__ __align__(16) unsigned short sV[96][72];   // [dh][key], pad 64->72
  __shared__ __align__(16) unsigned short sP[4][16][72];

  if (blockIdx.x >= 1024) {
    // ===================== aggregation path =====================
    if (threadIdx.x >= 192) return;     // 3 waves x 4 dims = 768
    const int abid = blockIdx.x - 1024;
    const int b = abid & 7, n = abid >> 3;   // batch -> XCD (bid%8 dispatch)
    const int bn = (b << 10) + n;
    const int d = threadIdx.x * 4;
    const float dn = dinv[bn];
    const size_t hrow = (size_t)bn * 768;
    ushort4 hv = *(const ushort4*)(h16 + hrow + d);
    float a0 = dn * dn * b2f(hv.x), a1 = dn * dn * b2f(hv.y);
    float a2 = dn * dn * b2f(hv.z), a3 = dn * dn * b2f(hv.w);
    const int st = offs[bn], cv = cnt[bn];
    const int* ep = elist + (b << 14) + st;
    int i = 0;
    for (; i + 2 <= cv; i += 2) {       // two independent gathers in flight
      const int s0 = ep[i], s1 = ep[i + 1];
      const float nv0 = dinv[(b << 10) + s0] * dn;
      const float nv1 = dinv[(b << 10) + s1] * dn;
      const ushort4 r0 = *(const ushort4*)(h16 + ((size_t)((b << 10) + s0)) * 768 + d);
      const ushort4 r1 = *(const ushort4*)(h16 + ((size_t)((b << 10) + s1)) * 768 + d);
      a0 += nv0 * b2f(r0.x) + nv1 * b2f(r1.x);
      a1 += nv0 * b2f(r0.y) + nv1 * b2f(r1.y);
      a2 += nv0 * b2f(r0.z) + nv1 * b2f(r1.z);
      a3 += nv0 * b2f(r0.w) + nv1 * b2f(r1.w);
    }
    if (i < cv) {
      const int s0 = ep[i];
      const float nv0 = dinv[(b << 10) + s0] * dn;
      const ushort4 r0 = *(const ushort4*)(h16 + ((size_t)((b << 10) + s0)) * 768 + d);
      a0 += nv0 * b2f(r0.x); a1 += nv0 * b2f(r0.y);
      a2 += nv0 * b2f(r0.z); a3 += nv0 * b2f(r0.w);
    }
    const float4 bb = *(const float4*)(gcn_b + d);
    a0 += bb.x; a1 += bb.y; a2 += bb.z; a3 += bb.w;
    const size_t crow = ((size_t)n * 8 + b) * 1536;
    ushort4 co; co.x = f2b(a0); co.y = f2b(a1); co.z = f2b(a2); co.w = f2b(a3);
    *(ushort4*)(cat16 + crow + d) = co;
    return;
  }

  // ===================== attention path =====================
  const int tid = threadIdx.x, lane = tid & 63, wid = tid >> 6;
  const int l15 = lane & 15, lhi = lane >> 4;
  const int bid = blockIdx.x;
  const int xcd = bid & 7, slot = bid >> 3;
  const int bh = xcd * 8 + (slot >> 4);
  const int q0 = (slot & 15) * 64;
  const float SCL = 0.14724445f;  // (1/sqrt(96)) * log2(e)

  b16x8 qf[3];
  const size_t qbase = ((size_t)bh * 1024 + q0 + wid * 16 + l15) * 96 + lhi * 8;
#pragma unroll
  for (int ks = 0; ks < 3; ++ks) qf[ks] = *(const b16x8*)(qb + qbase + ks * 32);

  const int c0 = tid, c1 = 256 + tid, c2 = 512 + tid;
  const unsigned short* kp0 = kb + ((size_t)bh * 1024 + c0 / 12) * 96 + (c0 % 12) * 8;
  const unsigned short* kp1 = kb + ((size_t)bh * 1024 + c1 / 12) * 96 + (c1 % 12) * 8;
  const unsigned short* kp2 = kb + ((size_t)bh * 1024 + c2 / 12) * 96 + (c2 % 12) * 8;
  const unsigned short* vp0 = vb + ((size_t)bh * 96 + (c0 >> 3)) * 1024 + (c0 & 7) * 8;
  const unsigned short* vp1 = vb + ((size_t)bh * 96 + (c1 >> 3)) * 1024 + (c1 & 7) * 8;
  const unsigned short* vp2 = vb + ((size_t)bh * 96 + (c2 >> 3)) * 1024 + (c2 & 7) * 8;
  unsigned short* sk0 = &sK[c0 / 12][(c0 % 12) * 8];
  unsigned short* sk1 = &sK[c1 / 12][(c1 % 12) * 8];
  unsigned short* sk2 = &sK[c2 / 12][(c2 % 12) * 8];
  unsigned short* sv0 = &sV[c0 >> 3][(c0 & 7) * 8];
  unsigned short* sv1 = &sV[c1 >> 3][(c1 & 7) * 8];
  unsigned short* sv2 = &sV[c2 >> 3][(c2 & 7) * 8];

  uint4 k0 = *(const uint4*)kp0, k1 = *(const uint4*)kp1, k2 = *(const uint4*)kp2;
  uint4 v0 = *(const uint4*)vp0, v1 = *(const uint4*)vp1, v2 = *(const uint4*)vp2;

  f32x4 accO[6] = {};
  float ssum[4] = {0.f, 0.f, 0.f, 0.f};

  for (int kt = 0; kt < 16; ++kt) {
    __syncthreads();
    *(uint4*)sk0 = k0; *(uint4*)sk1 = k1; *(uint4*)sk2 = k2;
    *(uint4*)sv0 = v0; *(uint4*)sv1 = v1; *(uint4*)sv2 = v2;
    __syncthreads();
    if (kt < 15) {
      kp0 += 64 * 96; kp1 += 64 * 96; kp2 += 64 * 96;
      vp0 += 64;      vp1 += 64;      vp2 += 64;
      k0 = *(const uint4*)kp0; k1 = *(const uint4*)kp1; k2 = *(const uint4*)kp2;
      v0 = *(const uint4*)vp0; v1 = *(const uint4*)vp1; v2 = *(const uint4*)vp2;
    }

    // S = Q K^T  (wave: 16 q-rows x 64 keys); T5 setprio vs agg waves
    f32x4 sf[4] = {};
    __builtin_amdgcn_s_setprio(1);
#pragma unroll
    for (int f = 0; f < 4; ++f) {
#pragma unroll
      for (int ks = 0; ks < 3; ++ks) {
        b16x8 kf = *(const b16x8*)&sK[f * 16 + l15][ks * 32 + lhi * 8];
        sf[f] = __builtin_amdgcn_mfma_f32_16x16x32_bf16(qf[ks], kf, sf[f], 0, 0, 0);
      }
    }
    __builtin_amdgcn_s_setprio(0);

#pragma unroll
    for (int g = 0; g < 4; ++g) {
#pragma unroll
      for (int f = 0; f < 4; ++f) {
        const float pv = exp2f(sf[f][g] * SCL);
        sP[wid][lhi * 4 + g][f * 16 + l15] = f2b(pv);
        ssum[g] += pv;
      }
    }

    // O += P V
    __builtin_amdgcn_s_setprio(1);
#pragma unroll
    for (int ks = 0; ks < 2; ++ks) {
      b16x8 pa = *(const b16x8*)&sP[wid][l15][ks * 32 + lhi * 8];
#pragma unroll
      for (int o = 0; o < 6; ++o) {
        b16x8 vf = *(const b16x8*)&sV[o * 16 + l15][ks * 32 + lhi * 8];
        accO[o] = __builtin_amdgcn_mfma_f32_16x16x32_bf16(pa, vf, accO[o], 0, 0, 0);
      }
    }
    __builtin_amdgcn_s_setprio(0);
  }

#pragma unroll
  for (int g = 0; g < 4; ++g) {
#pragma unroll
    for (int msk = 1; msk < 16; msk <<= 1) ssum[g] += __shfl_xor(ssum[g], msk);
  }

  const int b = bh >> 3, hd = bh & 7;
  float rinv[4];
#pragma unroll
  for (int g = 0; g < 4; ++g) rinv[g] = 1.0f / ssum[g];
#pragma unroll
  for (int o = 0; o < 6; ++o)
#pragma unroll
    for (int g = 0; g < 4; ++g) {
      const int qrow = q0 + wid * 16 + lhi * 4 + g;
      ctx[((size_t)qrow * 8 + b) * 768 + hd * 96 + o * 16 + l15] =
          f2b(accO[o][g] * rinv[g]);
    }
}

// ---------------------------------------------------------------------------
// gate-blend + residual + LayerNorm. block (192 thr) per row.
// ---------------------------------------------------------------------------
__global__ __launch_bounds__(192) void ln_fuse_kernel(
    const unsigned short* __restrict__ gate16,
    const unsigned short* __restrict__ cat16,
    const float* __restrict__ x,
    const float* __restrict__ lng, const float* __restrict__ lnb,
    float* __restrict__ out) {
  const int r = blockIdx.x;
  const int t = threadIdx.x, lane = t & 63, wid = t >> 6;   // 3 waves
  const int d = t * 4;
  const size_t xrow = (size_t)r * 768;
  const size_t crow = (size_t)r * 1536;
  const ushort4 gv = *(const ushort4*)(gate16 + xrow + d);
  const ushort4 cv = *(const ushort4*)(cat16 + crow + d);        // gcn
  const ushort4 av = *(const ushort4*)(cat16 + crow + 768 + d);  // attn
  const float4 xv = *(const float4*)(x + xrow + d);
  const float g0 = b2f(gv.x), g1 = b2f(gv.y), g2 = b2f(gv.z), g3 = b2f(gv.w);
  float f0 = g0 * b2f(cv.x) + (1.f - g0) * b2f(av.x) + xv.x;
  float f1 = g1 * b2f(cv.y) + (1.f - g1) * b2f(av.y) + xv.y;
  float f2 = g2 * b2f(cv.z) + (1.f - g2) * b2f(av.z) + xv.z;
  float f3 = g3 * b2f(cv.w) + (1.f - g3) * b2f(av.w) + xv.w;
  float s1 = f0 + f1 + f2 + f3;
  float s2 = f0 * f0 + f1 * f1 + f2 * f2 + f3 * f3;
#pragma unroll
  for (int msk = 1; msk < 64; msk <<= 1) {
    s1 += __shfl_xor(s1, msk);
    s2 += __shfl_xor(s2, msk);
  }
  __shared__ float p1[3], p2[3];
  if (lane == 0) { p1[wid] = s1; p2[wid] = s2; }
  __syncthreads();
  s1 = p1[0] + p1[1] + p1[2];
  s2 = p2[0] + p2[1] + p2[2];
  const float mu = s1 * (1.f / 768.f);
  float var = s2 * (1.f / 768.f) - mu * mu;
  var = fmaxf(var, 0.f);
  const float rstd = rsqrtf(var + LN_EPS);
  const float4 lg = *(const float4*)(lng + d);
  const float4 lb = *(const float4*)(lnb + d);
  float4 o;
  o.x = (f0 - mu) * rstd * lg.x + lb.x;
  o.y = (f1 - mu) * rstd * lg.y + lb.y;
  o.z = (f2 - mu) * rstd * lg.z + lb.z;
  o.w = (f3 - mu) * rstd * lg.w + lb.w;
  *(float4*)(out + xrow + d) = o;
}

// ---------------------------------------------------------------------------
extern "C" void kernel_launch(void* const* d_in, const int* in_sizes, int n_in,
                              void* d_out, int out_size, void* d_ws, size_t ws_size,
                              hipStream_t stream) {
  const float* x     = (const float*)d_in[0];
  const int*   ei    = (const int*)d_in[1];
  const float* gcnW  = (const float*)d_in[2];
  const float* gcnb  = (const float*)d_in[3];
  const float* ipw   = (const float*)d_in[4];
  const float* ipb   = (const float*)d_in[5];
  const float* opw   = (const float*)d_in[6];
  const float* opb   = (const float*)d_in[7];
  const float* gw    = (const float*)d_in[8];
  const float* gb    = (const float*)d_in[9];
  const float* lng   = (const float*)d_in[10];
  const float* lnb   = (const float*)d_in[11];
  float* out = (float*)d_out;

  char* p = (char*)d_ws;
  auto alloc = [&](size_t bytes) { void* q = p; p += (bytes + 255) & ~(size_t)255; return q; };

  unsigned short* xb16  = (unsigned short*)alloc((size_t)M * 768 * 2);   // also ctx16
  unsigned short* wcat  = (unsigned short*)alloc((size_t)3072 * 768 * 2); // [wgcn;wqkv]
  unsigned short* wout  = (unsigned short*)alloc((size_t)768 * 768 * 2);
  unsigned short* wgate = (unsigned short*)alloc((size_t)768 * 1536 * 2);
  unsigned short* qb    = (unsigned short*)alloc((size_t)B * H * N * DH * 2); // also gate16
  unsigned short* kb    = (unsigned short*)alloc((size_t)B * H * N * DH * 2);
  unsigned short* vb    = (unsigned short*)alloc((size_t)B * H * DH * N * 2);
  unsigned short* h16   = (unsigned short*)alloc((size_t)M * 768 * 2);
  unsigned short* cat16 = (unsigned short*)alloc((size_t)M * 1536 * 2);
  int* cnt    = (int*)alloc(8192 * 4);
  int* offs   = (int*)alloc(8192 * 4);
  int* cursor = (int*)alloc(8192 * 4);
  float* dinv = (float*)alloc(8192 * 4);
  int* elist  = (int*)alloc((size_t)B * E * 4);

  // safe aliases (serial-stream ordering makes these race-free):
  unsigned short* ctx16  = xb16;  // written by attn AFTER last read of xb16 (fused gemm)
  unsigned short* gate16 = qb;    // written by gate gemm AFTER attn reads qb

  // 1) zero degree counters (stream-ordered), then casts + edge_count
  hipMemsetAsync(cnt, 0, 8192 * 4, stream);
  cast_count_kernel<<<CAST_BLOCKS + CNT_BLOCKS, 256, 0, stream>>>(
      x, gcnW, ipw, opw, gw, xb16, wcat, wout, wgate, ei, cnt);

  // 2) CSR: scan + fill
  scan_offs_kernel<<<8, 1024, 0, stream>>>(cnt, offs, cursor, dinv);
  edge_fill_kernel<<<(B * E) / 256, 256, 0, stream>>>(ei, cursor, elist);

  // 3) fused GCN-linear + QKV GEMM; merged attn+agg; out-proj; gate
  gemm_bt<EPI_FUSED, 128, 768, 24, 64><<<1536, 256, 0, stream>>>(
      xb16, wcat, ipb, (void*)h16, (void*)qb, (void*)kb, (void*)vb);
  attn_agg_kernel<<<1024 + 8192, 256, 0, stream>>>(
      qb, kb, vb, ctx16, h16, cnt, offs, elist, dinv, gcnb, cat16);
  gemm_bt<EPI_ATTN, 64, 768, 12, 64><<<768, 256, 0, stream>>>(
      ctx16, wout, opb, (void*)cat16, nullptr, nullptr, nullptr);
  gemm_bt<EPI_GATE, 64, 1536, 12, 64><<<768, 256, 0, stream>>>(
      cat16, wgate, gb, (void*)gate16, nullptr, nullptr, nullptr);

  // 4) gate blend + residual + LayerNorm
  ln_fuse_kernel<<<8192, 192, 0, stream>>>(gate16, cat16, x, lng, lnb, out);
}